// Round 2
// baseline (111.667 us; speedup 1.0000x reference)
//
#include <hip/hip_runtime.h>

// Shapes: B=128, N=64, P=128, T=168
// x: [128,64,128] f32, x_i: [128,128] i32, g: [4096,4096] f32,
// weights: [4096,1] f32, alphas: [1,168] f32
// Out: Z [128,64] (8192 f32) then F [4096,168] (688128 f32), concat flat.
//
// Math: v = g @ w^2 (4096-vector); F = outer(v, alphas);
//       y[b,j] = sum_p alphas[xi[b,p]] * x[b,j,p]  (independent of v!)
//       Z[b,i] = sum_j v[i*64+j] * y[b,j]
//
// Structure: fuse the v/F row-dot and the y computation into ONE dispatch
// (y has no dependence on v, so its 4 MiB x-read overlaps the 64 MiB
// g-stream). Rowdot is wave-per-row: no LDS, no __syncthreads, butterfly
// shfl_xor only, 16 float4 loads/lane for deep HBM pipelining. Kernel 2 is a
// tiny L2-resident Z = V @ y (48 KB of reads).

#define GN 4096
#define TT 168
#define BB 128
#define NN 64
#define PP 128

// Native vector type for __builtin_nontemporal_load (HIP_vector_type is
// rejected by the builtin; ext_vector_type(4) float compiles to the same
// global_load_dwordx4).
typedef float vf4 __attribute__((ext_vector_type(4)));

// K1: blocks 0..127          : y[b,:] for b = blockIdx.x           -> ws
//     blocks 128..128+1023   : rows 4*(blk-128)+wave : v[row], F[row,:]
__global__ __launch_bounds__(256) void k_fused(
    const float* __restrict__ x, const int* __restrict__ xi,
    const float* __restrict__ g, const float* __restrict__ w,
    const float* __restrict__ alphas, float* __restrict__ v,
    float* __restrict__ y, float* __restrict__ Fout) {
  const int t = threadIdx.x;
  if (blockIdx.x >= BB) {
    // ---- row-dot: one wave per row, 4 rows per block ----
    const int rb = blockIdx.x - BB;
    const int wave = t >> 6, lane = t & 63;
    const int row = rb * 4 + wave;
    const vf4* g4 = (const vf4*)(g + (size_t)row * GN);
    const vf4* w4 = (const vf4*)w;
    float s = 0.f;
    // 4096 floats/row = 1024 float4 = 16 per lane. Nontemporal on g keeps the
    // 16 KB w vector resident in L1 across the stream.
#pragma unroll 8
    for (int it = 0; it < 16; ++it) {
      vf4 a = __builtin_nontemporal_load(&g4[it * 64 + lane]);
      vf4 b = w4[it * 64 + lane];
      s += a.x * (b.x * b.x) + a.y * (b.y * b.y) +
           a.z * (b.z * b.z) + a.w * (b.w * b.w);
    }
    // butterfly: all 64 lanes end with the row sum (no LDS, no barrier)
#pragma unroll
    for (int off = 32; off; off >>= 1) s += __shfl_xor(s, off, 64);
    if (lane == 0) v[row] = s;
    float* Frow = Fout + (size_t)row * TT;
    Frow[lane]      = s * alphas[lane];
    Frow[64 + lane] = s * alphas[64 + lane];
    if (lane < TT - 128) Frow[128 + lane] = s * alphas[128 + lane];
  } else {
    // ---- y: one block per batch b; 4 threads per output j ----
    const int b = blockIdx.x;
    __shared__ float ap[PP];
    if (t < PP) ap[t] = alphas[xi[b * PP + t]];
    __syncthreads();
    const int j = t >> 2, r = t & 3;  // thread (j,r) covers p in [32r, 32r+32)
    const float4* xrow4 =
        (const float4*)(x + (size_t)b * (NN * PP) + (size_t)j * PP + r * 32);
    const float4* ap4 = (const float4*)(ap + r * 32);
    float s = 0.f;
#pragma unroll
    for (int k = 0; k < 8; ++k) {
      float4 a = xrow4[k];
      float4 c = ap4[k];
      s += a.x * c.x + a.y * c.y + a.z * c.z + a.w * c.w;
    }
    // quad reduction (lanes 4j..4j+3 share a wave)
    s += __shfl_down(s, 2, 64);
    s += __shfl_down(s, 1, 64);
    if (r == 0) y[b * NN + j] = s;
  }
}

// K2: Z[b,i] = sum_j v[i*64+j] * y[b,j]. v (16 KB) + y (32 KB) are L2-hot.
__global__ __launch_bounds__(64) void k_z2(
    const float* __restrict__ v, const float* __restrict__ y,
    float* __restrict__ Z) {
  const int b = blockIdx.x, i = threadIdx.x;
  const float4* v4 = (const float4*)(v + i * NN);
  const float4* y4 = (const float4*)(y + b * NN);  // uniform across lanes
  float z = 0.f;
#pragma unroll
  for (int q = 0; q < 16; ++q) {
    float4 a = v4[q];
    float4 c = y4[q];
    z += a.x * c.x + a.y * c.y + a.z * c.z + a.w * c.w;
  }
  Z[b * NN + i] = z;
}

extern "C" void kernel_launch(void* const* d_in, const int* in_sizes, int n_in,
                              void* d_out, int out_size, void* d_ws, size_t ws_size,
                              hipStream_t stream) {
  const float* x      = (const float*)d_in[0];   // [128,64,128]
  const int*   xi     = (const int*)  d_in[1];   // [128,128]
  const float* g      = (const float*)d_in[2];   // [4096,4096]
  const float* w      = (const float*)d_in[3];   // [4096,1]
  const float* alphas = (const float*)d_in[4];   // [1,168]

  float* Z    = (float*)d_out;                   // [128,64]
  float* Fout = (float*)d_out + (BB * NN);       // [4096,168]
  float* v    = (float*)d_ws;                    // [4096]
  float* y    = (float*)d_ws + GN;               // [128*64]

  k_fused<<<BB + GN / 4, 256, 0, stream>>>(x, xi, g, w, alphas, v, y, Fout);
  k_z2<<<BB, 64, 0, stream>>>(v, y, Z);
}

// Round 3
// 104.294 us; speedup vs baseline: 1.0707x; 1.0707x over previous
//
#include <hip/hip_runtime.h>

// Shapes: B=128, N=64, P=128, T=168
// x: [128,64,128] f32, x_i: [128,128] i32, g: [4096,4096] f32,
// weights: [4096,1] f32, alphas: [1,168] f32
// Out: Z [128,64] (8192 f32) then F [4096,168] (688128 f32), concat flat.
//
// Math: v = g @ w^2 (4096-vector); F = outer(v, alphas);
//       y[b,j] = sum_p alphas[xi[b,p]] * x[b,j,p]  (independent of v!)
//       Z[b,i] = sum_j v[i*64+j] * y[b,j]
//
// Round 3: A/B vs round 2 — ONLY change is nontemporal → plain loads on the
// g-stream (nt forfeited cache residency / L2 burst aggregation; −8.9 µs
// regression attributed there). Fused structure kept identical.

#define GN 4096
#define TT 168
#define BB 128
#define NN 64
#define PP 128

// K1: blocks 0..127          : y[b,:] for b = blockIdx.x           -> ws
//     blocks 128..128+1023   : rows 4*(blk-128)+wave : v[row], F[row,:]
__global__ __launch_bounds__(256) void k_fused(
    const float* __restrict__ x, const int* __restrict__ xi,
    const float* __restrict__ g, const float* __restrict__ w,
    const float* __restrict__ alphas, float* __restrict__ v,
    float* __restrict__ y, float* __restrict__ Fout) {
  const int t = threadIdx.x;
  if (blockIdx.x >= BB) {
    // ---- row-dot: one wave per row, 4 rows per block ----
    const int rb = blockIdx.x - BB;
    const int wave = t >> 6, lane = t & 63;
    const int row = rb * 4 + wave;
    const float4* g4 = (const float4*)(g + (size_t)row * GN);
    const float4* w4 = (const float4*)w;
    float s = 0.f;
    // 4096 floats/row = 1024 float4 = 16 per lane; 8 loads in flight.
#pragma unroll 8
    for (int it = 0; it < 16; ++it) {
      float4 a = g4[it * 64 + lane];
      float4 b = w4[it * 64 + lane];
      s += a.x * (b.x * b.x) + a.y * (b.y * b.y) +
           a.z * (b.z * b.z) + a.w * (b.w * b.w);
    }
    // butterfly: all 64 lanes end with the row sum (no LDS, no barrier)
#pragma unroll
    for (int off = 32; off; off >>= 1) s += __shfl_xor(s, off, 64);
    if (lane == 0) v[row] = s;
    float* Frow = Fout + (size_t)row * TT;
    Frow[lane]      = s * alphas[lane];
    Frow[64 + lane] = s * alphas[64 + lane];
    if (lane < TT - 128) Frow[128 + lane] = s * alphas[128 + lane];
  } else {
    // ---- y: one block per batch b; 4 threads per output j ----
    const int b = blockIdx.x;
    __shared__ float ap[PP];
    if (t < PP) ap[t] = alphas[xi[b * PP + t]];
    __syncthreads();
    const int j = t >> 2, r = t & 3;  // thread (j,r) covers p in [32r, 32r+32)
    const float4* xrow4 =
        (const float4*)(x + (size_t)b * (NN * PP) + (size_t)j * PP + r * 32);
    const float4* ap4 = (const float4*)(ap + r * 32);
    float s = 0.f;
#pragma unroll
    for (int k = 0; k < 8; ++k) {
      float4 a = xrow4[k];
      float4 c = ap4[k];
      s += a.x * c.x + a.y * c.y + a.z * c.z + a.w * c.w;
    }
    // quad reduction (lanes 4j..4j+3 share a wave)
    s += __shfl_down(s, 2, 64);
    s += __shfl_down(s, 1, 64);
    if (r == 0) y[b * NN + j] = s;
  }
}

// K2: Z[b,i] = sum_j v[i*64+j] * y[b,j]. v (16 KB) + y (32 KB) are L2-hot.
__global__ __launch_bounds__(64) void k_z2(
    const float* __restrict__ v, const float* __restrict__ y,
    float* __restrict__ Z) {
  const int b = blockIdx.x, i = threadIdx.x;
  const float4* v4 = (const float4*)(v + i * NN);
  const float4* y4 = (const float4*)(y + b * NN);  // uniform across lanes
  float z = 0.f;
#pragma unroll
  for (int q = 0; q < 16; ++q) {
    float4 a = v4[q];
    float4 c = y4[q];
    z += a.x * c.x + a.y * c.y + a.z * c.z + a.w * c.w;
  }
  Z[b * NN + i] = z;
}

extern "C" void kernel_launch(void* const* d_in, const int* in_sizes, int n_in,
                              void* d_out, int out_size, void* d_ws, size_t ws_size,
                              hipStream_t stream) {
  const float* x      = (const float*)d_in[0];   // [128,64,128]
  const int*   xi     = (const int*)  d_in[1];   // [128,128]
  const float* g      = (const float*)d_in[2];   // [4096,4096]
  const float* w      = (const float*)d_in[3];   // [4096,1]
  const float* alphas = (const float*)d_in[4];   // [1,168]

  float* Z    = (float*)d_out;                   // [128,64]
  float* Fout = (float*)d_out + (BB * NN);       // [4096,168]
  float* v    = (float*)d_ws;                    // [4096]
  float* y    = (float*)d_ws + GN;               // [128*64]

  k_fused<<<BB + GN / 4, 256, 0, stream>>>(x, xi, g, w, alphas, v, y, Fout);
  k_z2<<<BB, 64, 0, stream>>>(v, y, Z);
}